// Round 2
// baseline (2557.802 us; speedup 1.0000x reference)
//
#include <hip/hip_runtime.h>
#include <hip/hip_bf16.h>
#include <hip/hip_cooperative_groups.h>
#include <cmath>

namespace cg = cooperative_groups;

typedef __bf16 bf16_t;
typedef bf16_t bf16x8 __attribute__((ext_vector_type(8)));
typedef float f32x4 __attribute__((ext_vector_type(4)));

#define B_ 32
#define T_ 64
#define D_ 512
#define H_ 1024
#define V_ 20000

// ---------------- cast ----------------
__global__ __launch_bounds__(256) void k_cast(const float* __restrict__ s,
                                              bf16_t* __restrict__ d, int n8) {
    int i = blockIdx.x * 256 + threadIdx.x;
    if (i >= n8) return;
    const f32x4* sv = (const f32x4*)s + (size_t)i * 2;
    f32x4 v0 = sv[0], v1 = sv[1];
    bf16x8 o;
    o[0] = (bf16_t)v0[0]; o[1] = (bf16_t)v0[1]; o[2] = (bf16_t)v0[2]; o[3] = (bf16_t)v0[3];
    o[4] = (bf16_t)v1[0]; o[5] = (bf16_t)v1[1]; o[6] = (bf16_t)v1[2]; o[7] = (bf16_t)v1[3];
    *((bf16x8*)d + i) = o;
}

// ---------------- async global->LDS helper ----------------
__device__ __forceinline__ void gl_lds16(const bf16_t* g, bf16_t* l) {
    __builtin_amdgcn_global_load_lds(
        (const __attribute__((address_space(1))) unsigned int*)g,
        (__attribute__((address_space(3))) unsigned int*)l, 16, 0, 0);
}

// ---------------- tiled GEMM: out[M x N] = A[M x K] * Bt[N x K]^T (+bias) ----------------
// 128x128 block tile, BK=64, 4 waves (2x2), 4x4 fragments/wave, LDS-staged.
template<bool EDGE, bool BIAS>
__global__ __launch_bounds__(256) void k_gemm_t(const bf16_t* __restrict__ A, int lda,
                                                const bf16_t* __restrict__ Bt, int ldb,
                                                int nkt, const float* __restrict__ bias,
                                                float* __restrict__ out, int ldo,
                                                int nmax, int nbn) {
    __shared__ bf16_t lA[128 * 64];
    __shared__ bf16_t lB[128 * 64];
    int bid = blockIdx.x;
    int bn = bid % nbn, bm = bid / nbn;
    int tid = threadIdx.x, w = tid >> 6, l = tid & 63;
    int wm = w >> 1, wn = w & 1;
    int lr = l & 15, lk = (l >> 4) << 3;
    int r0 = bm << 7, c0 = bn << 7;
    int chunkrow = l >> 3;
    int chunkcol = (l & 7) << 3;

    const bf16_t* srcA[4];
    const bf16_t* srcB[4];
#pragma unroll
    for (int i = 0; i < 4; ++i) {
        int rowt = ((w << 2) + i) << 3;       // (w*4+i)*8
        int ra = r0 + rowt + chunkrow;
        srcA[i] = A + (size_t)ra * lda + chunkcol;
        int rb = c0 + rowt + chunkrow;
        if (EDGE) rb = rb < nmax ? rb : nmax - 1;
        srcB[i] = Bt + (size_t)rb * ldb + chunkcol;
    }

    f32x4 acc[4][4] = {};
    for (int kt = 0; kt < nkt; ++kt) {
        __syncthreads();
#pragma unroll
        for (int i = 0; i < 4; ++i) {
            gl_lds16(srcA[i] + (kt << 6), lA + ((((w << 2) + i)) << 9));
            gl_lds16(srcB[i] + (kt << 6), lB + ((((w << 2) + i)) << 9));
        }
        __syncthreads();
#pragma unroll
        for (int kk = 0; kk < 2; ++kk) {
            bf16x8 af[4], bfr[4];
#pragma unroll
            for (int i = 0; i < 4; ++i)
                af[i] = *(const bf16x8*)&lA[(((wm << 6) + (i << 4) + lr) << 6) + (kk << 5) + lk];
#pragma unroll
            for (int j = 0; j < 4; ++j)
                bfr[j] = *(const bf16x8*)&lB[(((wn << 6) + (j << 4) + lr) << 6) + (kk << 5) + lk];
#pragma unroll
            for (int i = 0; i < 4; ++i)
#pragma unroll
                for (int j = 0; j < 4; ++j)
                    acc[i][j] = __builtin_amdgcn_mfma_f32_16x16x32_bf16(af[i], bfr[j], acc[i][j], 0, 0, 0);
        }
    }

    int crow = (l >> 4) << 2;
#pragma unroll
    for (int j = 0; j < 4; ++j) {
        int col = c0 + (wn << 6) + (j << 4) + lr;
        if (EDGE && col >= nmax) continue;
        float bl = BIAS ? bias[col] : 0.f;
#pragma unroll
        for (int i = 0; i < 4; ++i) {
            int row = r0 + (wm << 6) + (i << 4) + crow;
#pragma unroll
            for (int r = 0; r < 4; ++r)
                out[(size_t)(row + r) * ldo + col] = acc[i][j][r] + bl;
        }
    }
}

// ---------------- persistent cooperative LSTM recurrence ----------------
// 256 blocks x 512 threads. Block owns 4 H-cols x 4 gates = 16 W_hh rows,
// whose MFMA B-fragments persist in registers across all 64 steps.
// Per step: gates = h_{t-1} @ Whh^T (8-way K-split over waves, MFMA) + xw[t] + bias;
// LDS reduce; 128 threads do the cell update (c state in registers); grid sync.
__global__ __launch_bounds__(512) void k_recur(const bf16_t* __restrict__ h0,
                                               const bf16_t* __restrict__ Whh,   // [4096][1024]
                                               const float* __restrict__ xw,     // [2048][4096]
                                               const float* __restrict__ bih,
                                               const float* __restrict__ bhh,
                                               bf16_t* __restrict__ h_all) {     // [2048][1024], row m=b*64+t
    __shared__ float lds_part[8][32][16];
    __shared__ float lds_g[32][16];
    int tid = threadIdx.x, w = tid >> 6, l = tid & 63;
    int bid = blockIdx.x;
    int lr = l & 15, lk = (l >> 4) << 3;
    int kbase = w << 7;   // wave's 128-wide K slice

    // persistent W fragments: output col n = lr -> W-row = (n>>2)*1024 + bid*4 + (n&3)
    int wrow = ((lr >> 2) << 10) + (bid << 2) + (lr & 3);
    const bf16_t* wp = Whh + (size_t)wrow * H_ + kbase + lk;
    bf16x8 wf0 = *(const bf16x8*)(wp);
    bf16x8 wf1 = *(const bf16x8*)(wp + 32);
    bf16x8 wf2 = *(const bf16x8*)(wp + 64);
    bf16x8 wf3 = *(const bf16x8*)(wp + 96);

    // reduce-phase identity
    int rb = tid >> 4, rn = tid & 15;
    int gidx = ((rn >> 2) << 10) + (bid << 2) + (rn & 3);
    float btot = bih[gidx] + bhh[gidx];

    // cell-update identity (threads 0..127)
    float cst = 0.f;
    int ub = tid >> 2, uc = tid & 3;
    int hcol = (bid << 2) + uc;

    cg::grid_group grid = cg::this_grid();

    for (int t = 0; t < T_; ++t) {
        const bf16_t* hb;
        int hshift;
        if (t == 0) { hb = h0; hshift = 10; }
        else        { hb = h_all + (size_t)(t - 1) * H_; hshift = 16; }
        const bf16_t* pa0 = hb + ((size_t)lr << hshift) + kbase + lk;
        const bf16_t* pa1 = hb + ((size_t)(lr + 16) << hshift) + kbase + lk;

        f32x4 acc0 = {}, acc1 = {};
#pragma unroll
        for (int kt = 0; kt < 4; ++kt) {
            bf16x8 a0 = *(const bf16x8*)(pa0 + kt * 32);
            bf16x8 a1 = *(const bf16x8*)(pa1 + kt * 32);
            bf16x8 wf = (kt == 0) ? wf0 : (kt == 1) ? wf1 : (kt == 2) ? wf2 : wf3;
            acc0 = __builtin_amdgcn_mfma_f32_16x16x32_bf16(a0, wf, acc0, 0, 0, 0);
            acc1 = __builtin_amdgcn_mfma_f32_16x16x32_bf16(a1, wf, acc1, 0, 0, 0);
        }

        int crow = (l >> 4) << 2;
#pragma unroll
        for (int r = 0; r < 4; ++r) {
            lds_part[w][crow + r][lr]      = acc0[r];
            lds_part[w][16 + crow + r][lr] = acc1[r];
        }
        __syncthreads();

        float gsum = btot + xw[(size_t)((rb << 6) + t) * 4096 + gidx];
#pragma unroll
        for (int ww = 0; ww < 8; ++ww) gsum += lds_part[ww][rb][rn];
        lds_g[rb][rn] = gsum;
        __syncthreads();

        if (tid < 128) {
            float xi = lds_g[ub][uc];
            float xf = lds_g[ub][4 + uc];
            float xg = lds_g[ub][8 + uc];
            float xo = lds_g[ub][12 + uc];
            float ig = 1.f / (1.f + __expf(-xi));
            float fg = 1.f / (1.f + __expf(-xf));
            float gg = tanhf(xg);
            float og = 1.f / (1.f + __expf(-xo));
            cst = fg * cst + ig * gg;
            float hn = og * tanhf(cst);
            h_all[(size_t)((ub << 6) + t) * H_ + hcol] = (bf16_t)hn;
        }
        grid.sync();
    }
}

// ---------------- fused log-softmax (one block per row, in-place) ----------------
__global__ __launch_bounds__(256) void k_lsesub(float* __restrict__ out) {
    int m = blockIdx.x, tid = threadIdx.x;
    f32x4* row = (f32x4*)(out + (size_t)m * V_);
    float mx = -3.4e38f, s = 0.f;
    for (int i = tid; i < V_ / 4; i += 256) {
        f32x4 v = row[i];
#pragma unroll
        for (int j = 0; j < 4; ++j) {
            float x = v[j];
            if (x > mx) { s = s * __expf(mx - x) + 1.f; mx = x; }
            else        { s += __expf(x - mx); }
        }
    }
#pragma unroll
    for (int off = 1; off < 64; off <<= 1) {
        float m2 = __shfl_xor(mx, off);
        float s2 = __shfl_xor(s, off);
        float nm = fmaxf(mx, m2);
        s = s * __expf(mx - nm) + s2 * __expf(m2 - nm);
        mx = nm;
    }
    __shared__ float lm[4], lssh[4], Lsh;
    int w = tid >> 6;
    if ((tid & 63) == 0) { lm[w] = mx; lssh[w] = s; }
    __syncthreads();
    if (tid == 0) {
        float M = lm[0], S = lssh[0];
#pragma unroll
        for (int i = 1; i < 4; ++i) {
            float nm = fmaxf(M, lm[i]);
            S = S * __expf(M - nm) + lssh[i] * __expf(lm[i] - nm);
            M = nm;
        }
        Lsh = M + __logf(S);
    }
    __syncthreads();
    float L = Lsh;
    for (int i = tid; i < V_ / 4; i += 256) {
        f32x4 v = row[i];
        v[0] -= L; v[1] -= L; v[2] -= L; v[3] -= L;
        row[i] = v;
    }
}

// ---------------- launch ----------------
extern "C" void kernel_launch(void* const* d_in, const int* in_sizes, int n_in,
                              void* d_out, int out_size, void* d_ws, size_t ws_size,
                              hipStream_t stream) {
    const float* isequence = (const float*)d_in[0];  // [B][T][D]
    const float* hidden    = (const float*)d_in[1];  // [B][H]
    const float* W_ih      = (const float*)d_in[2];  // [4H][D]
    const float* W_hh      = (const float*)d_in[3];  // [4H][H]
    const float* b_ih      = (const float*)d_in[4];
    const float* b_hh      = (const float*)d_in[5];
    const float* W_lin     = (const float*)d_in[6];  // [V][H]
    const float* b_lin     = (const float*)d_in[7];
    float* out = (float*)d_out;

    auto pad = [](size_t x) { return (x + 255) & ~(size_t)255; };
    const size_t SZ_HALL = (size_t)B_ * T_ * H_ * 2;        // 4 MB
    const size_t SZ_WLIN = (size_t)V_ * H_ * 2;             // 41 MB
    const size_t SZ_X    = (size_t)B_ * T_ * D_ * 2;        // 2 MB
    const size_t SZ_WIH  = (size_t)4 * H_ * D_ * 2;         // 4 MB
    const size_t SZ_WHH  = (size_t)4 * H_ * H_ * 2;         // 8 MB
    const size_t SZ_H0   = (size_t)B_ * H_ * 2;             // 64 KB
    const size_t SZ_XW   = (size_t)B_ * T_ * 4 * H_ * 4;    // 32 MB (f32)
    size_t needB = pad(SZ_HALL) + pad(SZ_WLIN);
    size_t needA = pad(SZ_X) + pad(SZ_WIH) + pad(SZ_WHH) + pad(SZ_H0) + pad(SZ_XW);

    char* wsb = (char*)d_ws;
    // group B lives until the logits GEMM; group A is dead before d_out's first
    // write, so it can overlay d_out when ws is small.
    char* arenaA = (ws_size >= needA + needB) ? (wsb + needB) : (char*)d_out;

    bf16_t* h_all   = (bf16_t*)wsb;
    bf16_t* wlin_bf = (bf16_t*)(wsb + pad(SZ_HALL));
    bf16_t* x_bf    = (bf16_t*)arenaA;
    bf16_t* wih_bf  = (bf16_t*)(arenaA + pad(SZ_X));
    bf16_t* whh_bf  = (bf16_t*)(arenaA + pad(SZ_X) + pad(SZ_WIH));
    bf16_t* h0_bf   = (bf16_t*)(arenaA + pad(SZ_X) + pad(SZ_WIH) + pad(SZ_WHH));
    float*  xw      = (float*)(arenaA + pad(SZ_X) + pad(SZ_WIH) + pad(SZ_WHH) + pad(SZ_H0));

    // casts
    k_cast<<<(B_ * T_ * D_ / 8 + 255) / 256, 256, 0, stream>>>(isequence, x_bf, B_ * T_ * D_ / 8);
    k_cast<<<(V_ * H_ / 8 + 255) / 256, 256, 0, stream>>>(W_lin, wlin_bf, V_ * H_ / 8);
    k_cast<<<(4 * H_ * D_ / 8 + 255) / 256, 256, 0, stream>>>(W_ih, wih_bf, 4 * H_ * D_ / 8);
    k_cast<<<(4 * H_ * H_ / 8 + 255) / 256, 256, 0, stream>>>(W_hh, whh_bf, 4 * H_ * H_ / 8);
    k_cast<<<(B_ * H_ / 8 + 255) / 256, 256, 0, stream>>>(hidden, h0_bf, B_ * H_ / 8);

    // xw[m][4H] = x[m][:] @ W_ih^T   (M=2048, N=4096, K=512)
    k_gemm_t<false, false><<<32 * 16, 256, 0, stream>>>(x_bf, D_, wih_bf, D_, D_ / 64,
                                                        nullptr, xw, 4 * H_, 4 * H_, 32);

    // persistent recurrence
    {
        const bf16_t* a0 = h0_bf; const bf16_t* a1 = whh_bf; const float* a2 = xw;
        const float* a3 = b_ih; const float* a4 = b_hh; bf16_t* a5 = h_all;
        void* kargs[] = {&a0, &a1, &a2, &a3, &a4, &a5};
        hipLaunchCooperativeKernel((void*)k_recur, dim3(256), dim3(512), kargs, 0, stream);
    }

    // logits GEMM (M=2048, N=20000, K=1024) + bias
    int nbn = (V_ + 127) / 128;  // 157
    k_gemm_t<true, true><<<nbn * (B_ * T_ / 128), 256, 0, stream>>>(h_all, H_, wlin_bf, H_,
                                                                    H_ / 64, b_lin, out, V_, V_, nbn);
    // fused log-softmax
    k_lsesub<<<B_ * T_, 256, 0, stream>>>(out);
}

// Round 4
// 1036.479 us; speedup vs baseline: 2.4678x; 2.4678x over previous
//
#include <hip/hip_runtime.h>
#include <hip/hip_bf16.h>
#include <cmath>

typedef __bf16 bf16_t;
typedef bf16_t bf16x8 __attribute__((ext_vector_type(8)));
typedef float f32x4 __attribute__((ext_vector_type(4)));
typedef unsigned long long ull_t;

#define B_ 32
#define T_ 64
#define D_ 512
#define H_ 1024
#define V_ 20000

// ---------------- cast ----------------
__global__ __launch_bounds__(256) void k_cast(const float* __restrict__ s,
                                              bf16_t* __restrict__ d, int n8) {
    int i = blockIdx.x * 256 + threadIdx.x;
    if (i >= n8) return;
    const f32x4* sv = (const f32x4*)s + (size_t)i * 2;
    f32x4 v0 = sv[0], v1 = sv[1];
    bf16x8 o;
    o[0] = (bf16_t)v0[0]; o[1] = (bf16_t)v0[1]; o[2] = (bf16_t)v0[2]; o[3] = (bf16_t)v0[3];
    o[4] = (bf16_t)v1[0]; o[5] = (bf16_t)v1[1]; o[6] = (bf16_t)v1[2]; o[7] = (bf16_t)v1[3];
    *((bf16x8*)d + i) = o;
}

// ---------------- async global->LDS helper ----------------
__device__ __forceinline__ void gl_lds16(const bf16_t* g, bf16_t* l) {
    __builtin_amdgcn_global_load_lds(
        (const __attribute__((address_space(1))) unsigned int*)g,
        (__attribute__((address_space(3))) unsigned int*)l, 16, 0, 0);
}

// ---------------- tiled GEMM: out[M x N] = A[M x K] * Bt[N x K]^T (+bias) ----------------
// 128x128 block tile, BK=64, 4 waves (2x2), 4x4 fragments/wave, LDS-staged.
// XCD-aware bijective swizzle (grid must be divisible by 8; cpx = grid/8).
template<bool EDGE, bool BIAS>
__global__ __launch_bounds__(256) void k_gemm_t(const bf16_t* __restrict__ A, int lda,
                                                const bf16_t* __restrict__ Bt, int ldb,
                                                int nkt, const float* __restrict__ bias,
                                                float* __restrict__ out, int ldo,
                                                int nmax, int nbn, int cpx) {
    __shared__ bf16_t lA[128 * 64];
    __shared__ bf16_t lB[128 * 64];
    int bid = (blockIdx.x & 7) * cpx + (blockIdx.x >> 3);
    int bn = bid % nbn, bm = bid / nbn;
    int tid = threadIdx.x, w = tid >> 6, l = tid & 63;
    int wm = w >> 1, wn = w & 1;
    int lr = l & 15, lk = (l >> 4) << 3;
    int r0 = bm << 7, c0 = bn << 7;
    int chunkrow = l >> 3;
    int chunkcol = (l & 7) << 3;

    const bf16_t* srcA[4];
    const bf16_t* srcB[4];
#pragma unroll
    for (int i = 0; i < 4; ++i) {
        int rowt = ((w << 2) + i) << 3;       // (w*4+i)*8
        int ra = r0 + rowt + chunkrow;
        srcA[i] = A + (size_t)ra * lda + chunkcol;
        int rb = c0 + rowt + chunkrow;
        if (EDGE) rb = rb < nmax ? rb : nmax - 1;
        srcB[i] = Bt + (size_t)rb * ldb + chunkcol;
    }

    f32x4 acc[4][4] = {};
    for (int kt = 0; kt < nkt; ++kt) {
        __syncthreads();
#pragma unroll
        for (int i = 0; i < 4; ++i) {
            gl_lds16(srcA[i] + (kt << 6), lA + ((((w << 2) + i)) << 9));
            gl_lds16(srcB[i] + (kt << 6), lB + ((((w << 2) + i)) << 9));
        }
        __syncthreads();
#pragma unroll
        for (int kk = 0; kk < 2; ++kk) {
            bf16x8 af[4], bfr[4];
#pragma unroll
            for (int i = 0; i < 4; ++i)
                af[i] = *(const bf16x8*)&lA[(((wm << 6) + (i << 4) + lr) << 6) + (kk << 5) + lk];
#pragma unroll
            for (int j = 0; j < 4; ++j)
                bfr[j] = *(const bf16x8*)&lB[(((wn << 6) + (j << 4) + lr) << 6) + (kk << 5) + lk];
#pragma unroll
            for (int i = 0; i < 4; ++i)
#pragma unroll
                for (int j = 0; j < 4; ++j)
                    acc[i][j] = __builtin_amdgcn_mfma_f32_16x16x32_bf16(af[i], bfr[j], acc[i][j], 0, 0, 0);
        }
    }

    int crow = (l >> 4) << 2;
#pragma unroll
    for (int j = 0; j < 4; ++j) {
        int col = c0 + (wn << 6) + (j << 4) + lr;
        if (EDGE && col >= nmax) continue;
        float bl = BIAS ? bias[col] : 0.f;
#pragma unroll
        for (int i = 0; i < 4; ++i) {
            int row = r0 + (wm << 6) + (i << 4) + crow;
#pragma unroll
            for (int r = 0; r < 4; ++r)
                out[(size_t)(row + r) * ldo + col] = acc[i][j][r] + bl;
        }
    }
}

// ---------------- persistent LSTM recurrence, hand-rolled barrier ----------------
// 256 blocks x 512 threads (cooperative launch for co-residency; NO grid.sync).
// Block owns 4 H-cols x 4 gates = 16 W_hh rows; B-fragments persist in registers.
// Cross-block h exchange via AGENT-scope relaxed atomics (sc0/sc1 -> coherence
// point, no cache flushes). Per-step barrier: 8 group counters + 1 root, fresh
// counters per step (no reset), spin with s_sleep.
__global__ __launch_bounds__(512) void k_recur(const bf16_t* __restrict__ h0,
                                               const bf16_t* __restrict__ Whh,   // [4096][1024]
                                               const float* __restrict__ xw,     // [2048][4096]
                                               const float* __restrict__ bih,
                                               const float* __restrict__ bhh,
                                               bf16_t* __restrict__ h_all,       // [2048][1024], m=b*64+t
                                               unsigned* __restrict__ bar) {     // [64][9] counters, stride 16
    __shared__ float lds_part[8][32][17];
    __shared__ float lds_g[32][17];
    int tid = threadIdx.x, w = tid >> 6, l = tid & 63;
    int bid = blockIdx.x;
    int lr = l & 15, lk = (l >> 4) << 3;
    int kbase = w << 7;   // wave's 128-wide K slice

    // persistent W fragments: output col n = lr -> W-row = (n>>2)*1024 + bid*4 + (n&3)
    int wrow = ((lr >> 2) << 10) + (bid << 2) + (lr & 3);
    const bf16_t* wp = Whh + (size_t)wrow * H_ + kbase + lk;
    bf16x8 wf0 = *(const bf16x8*)(wp);
    bf16x8 wf1 = *(const bf16x8*)(wp + 32);
    bf16x8 wf2 = *(const bf16x8*)(wp + 64);
    bf16x8 wf3 = *(const bf16x8*)(wp + 96);

    // reduce-phase identity
    int rb = tid >> 4, rn = tid & 15;
    int gidx = ((rn >> 2) << 10) + (bid << 2) + (rn & 3);
    float btot = bih[gidx] + bhh[gidx];

    // cell state: threads 0..31, 4 cols each, registers
    float creg[4] = {0.f, 0.f, 0.f, 0.f};

    for (int t = 0; t < T_; ++t) {
        const ull_t* pa0;
        const ull_t* pa1;
        if (t == 0) {
            pa0 = (const ull_t*)(h0 + ((size_t)lr << 10) + kbase + lk);
            pa1 = (const ull_t*)(h0 + ((size_t)(lr + 16) << 10) + kbase + lk);
        } else {
            const bf16_t* hb = h_all + (size_t)(t - 1) * H_;
            pa0 = (const ull_t*)(hb + ((size_t)lr << 16) + kbase + lk);
            pa1 = (const ull_t*)(hb + ((size_t)(lr + 16) << 16) + kbase + lk);
        }
        // coherent h loads (bypass per-XCD L2)
        union { ull_t u[2]; bf16x8 v; } a0[4], a1[4];
#pragma unroll
        for (int kt = 0; kt < 4; ++kt) {
            a0[kt].u[0] = __hip_atomic_load(pa0 + kt * 8,     __ATOMIC_RELAXED, __HIP_MEMORY_SCOPE_AGENT);
            a0[kt].u[1] = __hip_atomic_load(pa0 + kt * 8 + 1, __ATOMIC_RELAXED, __HIP_MEMORY_SCOPE_AGENT);
            a1[kt].u[0] = __hip_atomic_load(pa1 + kt * 8,     __ATOMIC_RELAXED, __HIP_MEMORY_SCOPE_AGENT);
            a1[kt].u[1] = __hip_atomic_load(pa1 + kt * 8 + 1, __ATOMIC_RELAXED, __HIP_MEMORY_SCOPE_AGENT);
        }

        f32x4 acc0 = {}, acc1 = {};
        acc0 = __builtin_amdgcn_mfma_f32_16x16x32_bf16(a0[0].v, wf0, acc0, 0, 0, 0);
        acc1 = __builtin_amdgcn_mfma_f32_16x16x32_bf16(a1[0].v, wf0, acc1, 0, 0, 0);
        acc0 = __builtin_amdgcn_mfma_f32_16x16x32_bf16(a0[1].v, wf1, acc0, 0, 0, 0);
        acc1 = __builtin_amdgcn_mfma_f32_16x16x32_bf16(a1[1].v, wf1, acc1, 0, 0, 0);
        acc0 = __builtin_amdgcn_mfma_f32_16x16x32_bf16(a0[2].v, wf2, acc0, 0, 0, 0);
        acc1 = __builtin_amdgcn_mfma_f32_16x16x32_bf16(a1[2].v, wf2, acc1, 0, 0, 0);
        acc0 = __builtin_amdgcn_mfma_f32_16x16x32_bf16(a0[3].v, wf3, acc0, 0, 0, 0);
        acc1 = __builtin_amdgcn_mfma_f32_16x16x32_bf16(a1[3].v, wf3, acc1, 0, 0, 0);

        int crow = (l >> 4) << 2;
#pragma unroll
        for (int r = 0; r < 4; ++r) {
            lds_part[w][crow + r][lr]      = acc0[r];
            lds_part[w][16 + crow + r][lr] = acc1[r];
        }
        __syncthreads();

        float gsum = btot + xw[(size_t)(((rb << 6) + t) << 12) + gidx];
#pragma unroll
        for (int ww = 0; ww < 8; ++ww) gsum += lds_part[ww][rb][rn];
        lds_g[rb][rn] = gsum;
        __syncthreads();

        if (tid < 32) {
            union { bf16_t b[4]; ull_t u; } hp;
#pragma unroll
            for (int j = 0; j < 4; ++j) {
                float xi = lds_g[tid][j];
                float xf = lds_g[tid][4 + j];
                float xg = lds_g[tid][8 + j];
                float xo = lds_g[tid][12 + j];
                float ig = 1.f / (1.f + __expf(-xi));
                float fg = 1.f / (1.f + __expf(-xf));
                float gg = tanhf(xg);
                float og = 1.f / (1.f + __expf(-xo));
                float cn = fg * creg[j] + ig * gg;
                creg[j] = cn;
                hp.b[j] = (bf16_t)(og * tanhf(cn));
            }
            __hip_atomic_store((ull_t*)(h_all + (size_t)((tid << 6) + t) * H_ + (bid << 2)),
                               hp.u, __ATOMIC_RELAXED, __HIP_MEMORY_SCOPE_AGENT);
        }

        if (t < T_ - 1) {
            __syncthreads();   // drains vmcnt in every wave -> h stores at coherence point
            if (tid == 0) {
                unsigned* grp  = bar + (size_t)(t * 9 + (bid & 7)) * 16;
                unsigned* root = bar + (size_t)(t * 9 + 8) * 16;
                unsigned old = __hip_atomic_fetch_add(grp, 1u, __ATOMIC_RELAXED, __HIP_MEMORY_SCOPE_AGENT);
                if (old == 31u)
                    __hip_atomic_fetch_add(root, 1u, __ATOMIC_RELAXED, __HIP_MEMORY_SCOPE_AGENT);
                int guard = 0;
                while (__hip_atomic_load(root, __ATOMIC_RELAXED, __HIP_MEMORY_SCOPE_AGENT) != 8u) {
                    __builtin_amdgcn_s_sleep(8);
                    if (++guard > (1 << 17)) break;   // bounded: fail visibly, never hang
                }
            }
            __syncthreads();
        }
    }
}

// ---------------- fused log-softmax (one block per row, in-place) ----------------
__global__ __launch_bounds__(256) void k_lsesub(float* __restrict__ out) {
    int m = blockIdx.x, tid = threadIdx.x;
    f32x4* row = (f32x4*)(out + (size_t)m * V_);
    float mx = -3.4e38f, s = 0.f;
    for (int i = tid; i < V_ / 4; i += 256) {
        f32x4 v = row[i];
#pragma unroll
        for (int j = 0; j < 4; ++j) {
            float x = v[j];
            if (x > mx) { s = s * __expf(mx - x) + 1.f; mx = x; }
            else        { s += __expf(x - mx); }
        }
    }
#pragma unroll
    for (int off = 1; off < 64; off <<= 1) {
        float m2 = __shfl_xor(mx, off);
        float s2 = __shfl_xor(s, off);
        float nm = fmaxf(mx, m2);
        s = s * __expf(mx - nm) + s2 * __expf(m2 - nm);
        mx = nm;
    }
    __shared__ float lm[4], lssh[4], Lsh;
    int w = tid >> 6;
    if ((tid & 63) == 0) { lm[w] = mx; lssh[w] = s; }
    __syncthreads();
    if (tid == 0) {
        float M = lm[0], S = lssh[0];
#pragma unroll
        for (int i = 1; i < 4; ++i) {
            float nm = fmaxf(M, lm[i]);
            S = S * __expf(M - nm) + lssh[i] * __expf(lm[i] - nm);
            M = nm;
        }
        Lsh = M + __logf(S);
    }
    __syncthreads();
    float L = Lsh;
    for (int i = tid; i < V_ / 4; i += 256) {
        f32x4 v = row[i];
        v[0] -= L; v[1] -= L; v[2] -= L; v[3] -= L;
        row[i] = v;
    }
}

// ---------------- launch ----------------
extern "C" void kernel_launch(void* const* d_in, const int* in_sizes, int n_in,
                              void* d_out, int out_size, void* d_ws, size_t ws_size,
                              hipStream_t stream) {
    const float* isequence = (const float*)d_in[0];  // [B][T][D]
    const float* hidden    = (const float*)d_in[1];  // [B][H]
    const float* W_ih      = (const float*)d_in[2];  // [4H][D]
    const float* W_hh      = (const float*)d_in[3];  // [4H][H]
    const float* b_ih      = (const float*)d_in[4];
    const float* b_hh      = (const float*)d_in[5];
    const float* W_lin     = (const float*)d_in[6];  // [V][H]
    const float* b_lin     = (const float*)d_in[7];
    float* out = (float*)d_out;

    auto pad = [](size_t x) { return (x + 255) & ~(size_t)255; };
    const size_t SZ_HALL = (size_t)B_ * T_ * H_ * 2;        // 4 MB
    const size_t SZ_WLIN = (size_t)V_ * H_ * 2;             // 41 MB
    const size_t SZ_BAR  = (size_t)T_ * 9 * 16 * 4;         // 36 KB barrier counters
    const size_t SZ_X    = (size_t)B_ * T_ * D_ * 2;        // 2 MB
    const size_t SZ_WIH  = (size_t)4 * H_ * D_ * 2;         // 4 MB
    const size_t SZ_WHH  = (size_t)4 * H_ * H_ * 2;         // 8 MB
    const size_t SZ_H0   = (size_t)B_ * H_ * 2;             // 64 KB
    const size_t SZ_XW   = (size_t)B_ * T_ * 4 * H_ * 4;    // 32 MB (f32)
    size_t needB = pad(SZ_HALL) + pad(SZ_WLIN) + pad(SZ_BAR);
    size_t needA = pad(SZ_X) + pad(SZ_WIH) + pad(SZ_WHH) + pad(SZ_H0) + pad(SZ_XW);

    char* wsb = (char*)d_ws;
    // group B lives until the logits GEMM; group A is dead before d_out's first
    // write, so it can overlay d_out when ws is small.
    char* arenaA = (ws_size >= needA + needB) ? (wsb + needB) : (char*)d_out;

    bf16_t*   h_all   = (bf16_t*)wsb;
    bf16_t*   wlin_bf = (bf16_t*)(wsb + pad(SZ_HALL));
    unsigned* bar     = (unsigned*)(wsb + pad(SZ_HALL) + pad(SZ_WLIN));
    bf16_t*   x_bf    = (bf16_t*)arenaA;
    bf16_t*   wih_bf  = (bf16_t*)(arenaA + pad(SZ_X));
    bf16_t*   whh_bf  = (bf16_t*)(arenaA + pad(SZ_X) + pad(SZ_WIH));
    bf16_t*   h0_bf   = (bf16_t*)(arenaA + pad(SZ_X) + pad(SZ_WIH) + pad(SZ_WHH));
    float*    xw      = (float*)(arenaA + pad(SZ_X) + pad(SZ_WIH) + pad(SZ_WHH) + pad(SZ_H0));

    // casts + barrier-counter zeroing
    k_cast<<<(B_ * T_ * D_ / 8 + 255) / 256, 256, 0, stream>>>(isequence, x_bf, B_ * T_ * D_ / 8);
    k_cast<<<(V_ * H_ / 8 + 255) / 256, 256, 0, stream>>>(W_lin, wlin_bf, V_ * H_ / 8);
    k_cast<<<(4 * H_ * D_ / 8 + 255) / 256, 256, 0, stream>>>(W_ih, wih_bf, 4 * H_ * D_ / 8);
    k_cast<<<(4 * H_ * H_ / 8 + 255) / 256, 256, 0, stream>>>(W_hh, whh_bf, 4 * H_ * H_ / 8);
    k_cast<<<(B_ * H_ / 8 + 255) / 256, 256, 0, stream>>>(hidden, h0_bf, B_ * H_ / 8);
    hipMemsetAsync(bar, 0, SZ_BAR, stream);

    // xw[m][4H] = x[m][:] @ W_ih^T   (M=2048, N=4096, K=512), grid 512 = 8*64
    k_gemm_t<false, false><<<32 * 16, 256, 0, stream>>>(x_bf, D_, wih_bf, D_, D_ / 64,
                                                        nullptr, xw, 4 * H_, 4 * H_, 32, 64);

    // persistent recurrence (cooperative for co-residency; custom barrier inside)
    {
        const bf16_t* a0 = h0_bf; const bf16_t* a1 = whh_bf; const float* a2 = xw;
        const float* a3 = b_ih; const float* a4 = b_hh; bf16_t* a5 = h_all;
        unsigned* a6 = bar;
        void* kargs[] = {&a0, &a1, &a2, &a3, &a4, &a5, &a6};
        hipLaunchCooperativeKernel((void*)k_recur, dim3(256), dim3(512), kargs, 0, stream);
    }

    // logits GEMM (M=2048, N=20000->20096, K=1024) + bias, grid 2512 = 8*314
    int nbn = (V_ + 127) / 128;  // 157
    k_gemm_t<true, true><<<nbn * (B_ * T_ / 128), 256, 0, stream>>>(h_all, H_, wlin_bf, H_,
                                                                    H_ / 64, b_lin, out, V_,
                                                                    V_, nbn, nbn * 16 / 8);
    // fused log-softmax
    k_lsesub<<<B_ * T_, 256, 0, stream>>>(out);
}